// Round 6
// baseline (847.194 us; speedup 1.0000x reference)
//
#include <hip/hip_runtime.h>
#include <hip/hip_bf16.h>
#include <math.h>

#define F_IN 512
#define H1   16
#define C2   40
#define BKL  6                 // log2(nodes per bucket)
#define BK   (1 << BKL)        // 64 nodes per bucket
#define NBMAX 2048
#define G    1024              // edge-chunk groups for count/fill
#define U    8                 // gather ILP depth in agg kernels
#define TPAD 128               // bucket edge-count padding (16 groups * U)

__device__ __forceinline__ float bf2f(unsigned short u) {
  union { unsigned int i; float f; } v; v.i = ((unsigned int)u) << 16; return v.f;
}
__device__ __forceinline__ unsigned short f2bf(float f) {
  __hip_bfloat16 b = __float2bfloat16(f);  // RNE
  return *reinterpret_cast<unsigned short*>(&b);
}

// ---------------- phase 1: per-chunk bucket histogram (LDS atomics only) ----------------
__global__ __launch_bounds__(256) void k_count(const int* __restrict__ dst,
                                               int* __restrict__ cnt,
                                               int E, int NB, int epb) {
  __shared__ int h[NBMAX];
  int g = blockIdx.x, t = threadIdx.x;
  for (int i = t; i < NB; i += 256) h[i] = 0;
  __syncthreads();
  int e0 = g * epb, e1 = min(e0 + epb, E);
  for (int e = e0 + t; e < e1; e += 256) atomicAdd(&h[dst[e] >> BKL], 1);
  __syncthreads();
  for (int i = t; i < NB; i += 256) cnt[g * NB + i] = h[i];
}

// ---------------- phase 2a: per-bucket exclusive scan over the G groups ----------------
__global__ __launch_bounds__(G) void k_scan_col(int* cnt, int* tot, int NB) {
  __shared__ int lds[G];
  int b = blockIdx.x, t = threadIdx.x;
  int v = cnt[t * NB + b];
  lds[t] = v;
  __syncthreads();
  for (int off = 1; off < G; off <<= 1) {
    int add = (t >= off) ? lds[t - off] : 0;
    __syncthreads();
    lds[t] += add;
    __syncthreads();
  }
  cnt[t * NB + b] = lds[t] - v;         // exclusive within bucket
  if (t == G - 1) tot[b] = lds[G - 1];  // bucket total (real edges)
}

// ---------------- phase 2b: exclusive scan of PADDED bucket totals ----------------
__global__ __launch_bounds__(512) void k_scan_tot(const int* __restrict__ tot,
                                                  int* bstart, int NB) {
  __shared__ int lds[512];
  int t = threadIdx.x;
  int b0 = t * 4;
  int v[4];
  int s = 0;
#pragma unroll
  for (int k = 0; k < 4; k++) {
    int tv = (b0 + k < NB) ? tot[b0 + k] : 0;
    v[k] = (tv + TPAD - 1) & ~(TPAD - 1);   // pad to multiple of TPAD
    s += v[k];
  }
  lds[t] = s;
  __syncthreads();
  for (int off = 1; off < 512; off <<= 1) {
    int add = (t >= off) ? lds[t - off] : 0;
    __syncthreads();
    lds[t] += add;
    __syncthreads();
  }
  int excl = lds[t] - s;
#pragma unroll
  for (int k = 0; k < 4; k++) {
    if (b0 + k < NB) bstart[b0 + k] = excl;
    excl += v[k];
  }
  if (t == 511) bstart[NB] = excl;  // padded grand total
}

// ---------------- phase 3: fill (LDS cursors, private sub-ranges, no global atomics) ----------------
__global__ __launch_bounds__(256) void k_fill(const int* __restrict__ src,
                                              const int* __restrict__ dst,
                                              const int* __restrict__ cnt,
                                              const int* __restrict__ bstart,
                                              unsigned* __restrict__ ebuf,
                                              int E, int NB, int epb) {
  __shared__ int cur[NBMAX];
  int g = blockIdx.x, t = threadIdx.x;
  for (int i = t; i < NB; i += 256) cur[i] = bstart[i] + cnt[g * NB + i];
  __syncthreads();
  int e0 = g * epb, e1 = min(e0 + epb, E);
  for (int e = e0 + t; e < e1; e += 256) {
    int d = dst[e];
    int pos = atomicAdd(&cur[d >> BKL], 1);
    ebuf[pos] = ((unsigned)src[e] << BKL) | (unsigned)(d & (BK - 1));
  }
}

// ---------------- phase 4: sentinel-pad each bucket to its padded end ----------------
__global__ __launch_bounds__(128) void k_pad(const int* __restrict__ tot,
                                             const int* __restrict__ bstart,
                                             unsigned* __restrict__ ebuf, int N) {
  int b = blockIdx.x, t = threadIdx.x;
  unsigned SENT = ((unsigned)N) << BKL;   // src = zero-row N, slot 0
  int s = bstart[b] + tot[b], e = bstart[b + 1];
  for (int i = s + t; i < e; i += 128) ebuf[i] = SENT;
}

// ---------------- zero the sentinel message row ----------------
__global__ __launch_bounds__(64) void k_zrow(unsigned short* g1bf, unsigned short* g2bf, int N) {
  int t = threadIdx.x;
  if (t < H1) { g1bf[(size_t)N * H1 + t] = 0; g2bf[(size_t)N * H1 + t] = 0; }
}

// ---------------- per-node degree from grouped ebuf (real range only) -> dinv ----------------
__global__ __launch_bounds__(256) void k_dinv2(const unsigned* __restrict__ ebuf,
                                               const int* __restrict__ bstart,
                                               const int* __restrict__ tot,
                                               float* __restrict__ dinv, int N) {
  __shared__ int c[BK];
  int b = blockIdx.x, t = threadIdx.x;
  if (t < BK) c[t] = 0;
  __syncthreads();
  int e0 = bstart[b], e1 = e0 + tot[b];
  for (int e = e0 + t; e < e1; e += 256) atomicAdd(&c[ebuf[e] & (BK - 1)], 1);
  __syncthreads();
  int node = b * BK + t;
  if (t < BK && node < N) dinv[node] = rsqrtf((float)(c[t] + 1));
}

// ---------------- g1 = bf16( (x @ W1) * dinv[row] ), 2 rows/wave ----------------
__global__ __launch_bounds__(256, 2) void k_gemm1(const float* __restrict__ x,
                                                  const float* __restrict__ W1,
                                                  const float* __restrict__ dinv,
                                                  unsigned short* __restrict__ g1bf, int N) {
  int lane = threadIdx.x & 63;
  int wid = (int)((blockIdx.x * (long long)blockDim.x + threadIdx.x) >> 6);
  int nw = (gridDim.x * blockDim.x) >> 6;

  float wr[128];
#pragma unroll
  for (int j = 0; j < 8; j++) {
    const float* wrow = &W1[(lane * 8 + j) * H1];
    float4 w0 = *(const float4*)&wrow[0];
    float4 w1 = *(const float4*)&wrow[4];
    float4 w2 = *(const float4*)&wrow[8];
    float4 w3 = *(const float4*)&wrow[12];
    wr[j*16+ 0]=w0.x; wr[j*16+ 1]=w0.y; wr[j*16+ 2]=w0.z; wr[j*16+ 3]=w0.w;
    wr[j*16+ 4]=w1.x; wr[j*16+ 5]=w1.y; wr[j*16+ 6]=w1.z; wr[j*16+ 7]=w1.w;
    wr[j*16+ 8]=w2.x; wr[j*16+ 9]=w2.y; wr[j*16+10]=w2.z; wr[j*16+11]=w2.w;
    wr[j*16+12]=w3.x; wr[j*16+13]=w3.y; wr[j*16+14]=w3.z; wr[j*16+15]=w3.w;
  }

  int row = wid * 2;
  int step = nw * 2;
  float4 A0 = make_float4(0,0,0,0), A1 = A0, B0 = A0, B1 = A0;
  if (row < N) {
    const float4* xr = (const float4*)(x + (size_t)row * F_IN);
    A0 = xr[lane * 2]; A1 = xr[lane * 2 + 1];
    if (row + 1 < N) {
      const float4* xr2 = (const float4*)(x + (size_t)(row + 1) * F_IN);
      B0 = xr2[lane * 2]; B1 = xr2[lane * 2 + 1];
    }
  }
  while (row < N) {
    int nrow = row + step;
    float4 nA0 = make_float4(0,0,0,0), nA1 = nA0, nB0 = nA0, nB1 = nA0;
    if (nrow < N) {
      const float4* xr = (const float4*)(x + (size_t)nrow * F_IN);
      nA0 = xr[lane * 2]; nA1 = xr[lane * 2 + 1];
      if (nrow + 1 < N) {
        const float4* xr2 = (const float4*)(x + (size_t)(nrow + 1) * F_IN);
        nB0 = xr2[lane * 2]; nB1 = xr2[lane * 2 + 1];
      }
    }
    float xa[8] = {A0.x, A0.y, A0.z, A0.w, A1.x, A1.y, A1.z, A1.w};
    float xb[8] = {B0.x, B0.y, B0.z, B0.w, B1.x, B1.y, B1.z, B1.w};
    float accA[16], accB[16];
#pragma unroll
    for (int c = 0; c < 16; c++) { accA[c] = 0.f; accB[c] = 0.f; }
#pragma unroll
    for (int j = 0; j < 8; j++)
#pragma unroll
      for (int c = 0; c < 16; c++) {
        accA[c] = fmaf(xa[j], wr[j * 16 + c], accA[c]);
        accB[c] = fmaf(xb[j], wr[j * 16 + c], accB[c]);
      }

    // two independent reduce-scatter butterflies (interleaved by scheduler)
    float a8[8], b8[8];
#pragma unroll
    for (int i = 0; i < 8; i++) {
      float t0 = accA[2*i]   + __shfl_xor(accA[2*i],   1, 64);
      float t1 = accA[2*i+1] + __shfl_xor(accA[2*i+1], 1, 64);
      a8[i] = (lane & 1) ? t1 : t0;
      float s0 = accB[2*i]   + __shfl_xor(accB[2*i],   1, 64);
      float s1 = accB[2*i+1] + __shfl_xor(accB[2*i+1], 1, 64);
      b8[i] = (lane & 1) ? s1 : s0;
    }
    float a4[4], b4[4];
#pragma unroll
    for (int i = 0; i < 4; i++) {
      float t0 = a8[2*i]   + __shfl_xor(a8[2*i],   2, 64);
      float t1 = a8[2*i+1] + __shfl_xor(a8[2*i+1], 2, 64);
      a4[i] = ((lane >> 1) & 1) ? t1 : t0;
      float s0 = b8[2*i]   + __shfl_xor(b8[2*i],   2, 64);
      float s1 = b8[2*i+1] + __shfl_xor(b8[2*i+1], 2, 64);
      b4[i] = ((lane >> 1) & 1) ? s1 : s0;
    }
    float a2[2], b2v[2];
#pragma unroll
    for (int i = 0; i < 2; i++) {
      float t0 = a4[2*i]   + __shfl_xor(a4[2*i],   4, 64);
      float t1 = a4[2*i+1] + __shfl_xor(a4[2*i+1], 4, 64);
      a2[i] = ((lane >> 2) & 1) ? t1 : t0;
      float s0 = b4[2*i]   + __shfl_xor(b4[2*i],   4, 64);
      float s1 = b4[2*i+1] + __shfl_xor(b4[2*i+1], 4, 64);
      b2v[i] = ((lane >> 2) & 1) ? s1 : s0;
    }
    float ta0 = a2[0] + __shfl_xor(a2[0], 8, 64);
    float ta1 = a2[1] + __shfl_xor(a2[1], 8, 64);
    float va = ((lane >> 3) & 1) ? ta1 : ta0;
    float tb0 = b2v[0] + __shfl_xor(b2v[0], 8, 64);
    float tb1 = b2v[1] + __shfl_xor(b2v[1], 8, 64);
    float vb = ((lane >> 3) & 1) ? tb1 : tb0;
    va += __shfl_xor(va, 16, 64); va += __shfl_xor(va, 32, 64);
    vb += __shfl_xor(vb, 16, 64); vb += __shfl_xor(vb, 32, 64);

    if (lane < 16) {
      g1bf[(size_t)row * H1 + lane] = f2bf(va * dinv[row]);
      if (row + 1 < N) g1bf[(size_t)(row + 1) * H1 + lane] = f2bf(vb * dinv[row + 1]);
    }
    row = nrow; A0 = nA0; A1 = nA1; B0 = nB0; B1 = nB1;
  }
}

// ---------------- layer-1 aggregate (guard-free padded loop) + relu epilogue ----------------
__global__ __launch_bounds__(256) void k_agg1(const unsigned* __restrict__ ebuf,
                                              const int* __restrict__ bstart,
                                              const unsigned short* __restrict__ g1bf,
                                              const float* __restrict__ dinv,
                                              const float* __restrict__ b1,
                                              unsigned short* __restrict__ g2bf, int N) {
  __shared__ float acc[BK * H1];  // 4 KB
  int t = threadIdx.x;
  int bb = blockIdx.x;
  for (int i = t; i < BK * H1; i += 256) acc[i] = 0.f;
  __syncthreads();

  int e0 = bstart[bb], e1 = bstart[bb + 1];  // (e1-e0) % 128 == 0
  int grp = t >> 4, j = t & 15;              // 16 edge-groups of 16 lanes
  for (int base = e0 + grp; base < e1; base += 16 * U) {
    unsigned p[U];
#pragma unroll
    for (int u = 0; u < U; u++) p[u] = ebuf[base + 16 * u];
    float v[U];
#pragma unroll
    for (int u = 0; u < U; u++) v[u] = bf2f(g1bf[(size_t)(p[u] >> BKL) * H1 + j]);
#pragma unroll
    for (int u = 0; u < U; u++) atomicAdd(&acc[(p[u] & (BK - 1)) * H1 + j], v[u]);
  }
  __syncthreads();

  if (t < BK * 2) {
    int nl = t >> 1, half = (t & 1) * 8;
    int node = bb * BK + nl;
    if (node < N) {
      float di = dinv[node];
      unsigned* dst32 = (unsigned*)g2bf + (size_t)node * (H1 / 2) + (half >> 1);
#pragma unroll
      for (int k = 0; k < 4; k++) {
        int jj = half + 2 * k;
        float v0 = di * (acc[nl * H1 + jj]     + bf2f(g1bf[(size_t)node * H1 + jj]))     + b1[jj];
        float v1 = di * (acc[nl * H1 + jj + 1] + bf2f(g1bf[(size_t)node * H1 + jj + 1])) + b1[jj + 1];
        v0 = fmaxf(v0, 0.f) * di;
        v1 = fmaxf(v1, 0.f) * di;
        dst32[k] = (unsigned)f2bf(v0) | ((unsigned)f2bf(v1) << 16);
      }
    }
  }
}

// ---------------- layer-2 aggregate (guard-free) -> s2 fp32 ----------------
__global__ __launch_bounds__(256) void k_agg2(const unsigned* __restrict__ ebuf,
                                              const int* __restrict__ bstart,
                                              const unsigned short* __restrict__ g2bf,
                                              const float* __restrict__ dinv,
                                              float* __restrict__ s2, int N) {
  __shared__ float acc[BK * H1];  // 4 KB
  int t = threadIdx.x;
  int bb = blockIdx.x;
  for (int i = t; i < BK * H1; i += 256) acc[i] = 0.f;
  __syncthreads();

  int e0 = bstart[bb], e1 = bstart[bb + 1];
  int grp = t >> 4, j = t & 15;
  for (int base = e0 + grp; base < e1; base += 16 * U) {
    unsigned p[U];
#pragma unroll
    for (int u = 0; u < U; u++) p[u] = ebuf[base + 16 * u];
    float v[U];
#pragma unroll
    for (int u = 0; u < U; u++) v[u] = bf2f(g2bf[(size_t)(p[u] >> BKL) * H1 + j]);
#pragma unroll
    for (int u = 0; u < U; u++) atomicAdd(&acc[(p[u] & (BK - 1)) * H1 + j], v[u]);
  }
  __syncthreads();

  if (t < BK * 2) {
    int nl = t >> 1, half = (t & 1) * 8;
    int node = bb * BK + nl;
    if (node < N) {
      float di = dinv[node];
#pragma unroll
      for (int k = 0; k < 8; k++) {
        int jj = half + k;
        s2[(size_t)node * H1 + jj] = di * (acc[nl * H1 + jj] + bf2f(g2bf[(size_t)node * H1 + jj]));
      }
    }
  }
}

// ---------------- final epilogue: out = log_softmax(s2 @ W2 + b2) ----------------
__global__ __launch_bounds__(256) void k_ep2(const float* __restrict__ s2,
                                             const float* __restrict__ W2,
                                             const float* __restrict__ b2,
                                             float* __restrict__ out, int N) {
  __shared__ float w2s[H1 * C2];
  __shared__ float b2s[C2];
  int t = threadIdx.x;
  for (int i = t; i < H1 * C2; i += 256) w2s[i] = W2[i];
  if (t < C2) b2s[t] = b2[t];
  __syncthreads();

  int lane = t & 63;
  int node = (int)((blockIdx.x * (long long)blockDim.x + t) >> 6);
  if (node >= N) return;
  float sv = (lane < H1) ? s2[(size_t)node * H1 + lane] : 0.f;
  int cl = (lane < C2) ? lane : 0;
  float z = b2s[cl];
#pragma unroll
  for (int jj = 0; jj < H1; jj++) {
    float sj = __shfl(sv, jj, 64);
    z = fmaf(sj, w2s[jj * C2 + cl], z);
  }
  if (lane >= C2) z = -INFINITY;
  float m = z;
#pragma unroll
  for (int off = 32; off; off >>= 1) m = fmaxf(m, __shfl_xor(m, off, 64));
  float p = (lane < C2) ? expf(z - m) : 0.f;
  float ssum = p;
#pragma unroll
  for (int off = 32; off; off >>= 1) ssum += __shfl_xor(ssum, off, 64);
  if (lane < C2) out[(size_t)node * C2 + lane] = z - m - logf(ssum);
}

extern "C" void kernel_launch(void* const* d_in, const int* in_sizes, int n_in,
                              void* d_out, int out_size, void* d_ws, size_t ws_size,
                              hipStream_t stream) {
  const float* x  = (const float*)d_in[0];
  const int*   ei = (const int*)d_in[1];
  const float* W1 = (const float*)d_in[2];
  const float* b1 = (const float*)d_in[3];
  const float* W2 = (const float*)d_in[4];
  const float* b2 = (const float*)d_in[5];
  float* out = (float*)d_out;

  int N = in_sizes[0] / F_IN;
  int E = in_sizes[1] / 2;
  const int* src = ei;
  const int* dst = ei + E;
  int NB = (N + BK - 1) / BK;     // 1563 for N=100000 (must be <= NBMAX)
  int epb = (E + G - 1) / G;      // edges per chunk group

  char* w = (char*)d_ws;
  size_t off = 0;
  auto alloc = [&](size_t bytes) { char* p = w + off; off = (off + bytes + 255) & ~(size_t)255; return p; };
  int*   cnt    = (int*)alloc((size_t)G * NB * 4);
  int*   tot    = (int*)alloc((size_t)NB * 4);
  int*   bstart = (int*)alloc((size_t)(NB + 1) * 4);
  float* dinv   = (float*)alloc((size_t)N * 4);
  unsigned* ebuf = (unsigned*)alloc(((size_t)E + (size_t)NB * TPAD) * 4);
  unsigned short* g1bf = (unsigned short*)alloc((size_t)(N + 1) * H1 * 2);
  unsigned short* g2bf = (unsigned short*)alloc((size_t)(N + 1) * H1 * 2);
  float* s2 = (float*)cnt;  // alias: cnt dead after k_fill; N*16*4 <= G*NB*4

  k_count   <<<G, 256, 0, stream>>>(dst, cnt, E, NB, epb);
  k_scan_col<<<NB, G, 0, stream>>>(cnt, tot, NB);
  k_scan_tot<<<1, 512, 0, stream>>>(tot, bstart, NB);
  k_fill    <<<G, 256, 0, stream>>>(src, dst, cnt, bstart, ebuf, E, NB, epb);
  k_pad     <<<NB, 128, 0, stream>>>(tot, bstart, ebuf, N);
  k_dinv2   <<<NB, 256, 0, stream>>>(ebuf, bstart, tot, dinv, N);
  k_zrow    <<<1, 64, 0, stream>>>(g1bf, g2bf, N);
  k_gemm1   <<<1024, 256, 0, stream>>>(x, W1, dinv, g1bf, N);
  k_agg1    <<<NB, 256, 0, stream>>>(ebuf, bstart, g1bf, dinv, b1, g2bf, N);
  k_agg2    <<<NB, 256, 0, stream>>>(ebuf, bstart, g2bf, dinv, s2, N);
  k_ep2     <<<(N * 64 + 255) / 256, 256, 0, stream>>>(s2, W2, b2, out, N);
}